// Round 12
// baseline (136.193 us; speedup 1.0000x reference)
//
#include <hip/hip_runtime.h>
#include <hip/hip_bf16.h>

// B=2,S=2048 -> T=4096 tokens; D=1024; N=64 experts; R=64; TOP_K=2.
// Inputs runtime-detected f32 vs bf16 (measured: f32). Outputs f32 flat:
// [0,262144) proj; [262144,270336) idx; [270336,278528) w.
// R21: score's 43us floor was an artifact of re-staging router_w EVERY
// chunk (16 latency-exposed barriers). rw K-quarter for all 64 experts =
// 64KB -> LDS-RESIDENT (egemm persistent-B pattern applied to score):
// 256 blocks = 4 K-quarters x 64 token-partitions; wt staged ONCE;
// loop 8 groups x 8 tokens staging only x (prefetched; each x byte read
// by exactly 1 block). M4xE8 compute core index-math cloned from the
// proven kernel; cross-wave reduce now parallel (per-wave scW partials +
// 4-way fixed-order sum) instead of 4 serialized wave phases.
// Sb = 4 quarter-partials (4MB); topk sums 4 in fixed order.
// topk(64x64)/egemm(2-deep prefetch)/combine identical to the 123.9 build.
// Harness d_ws poison fill (~44us, evicts L3 every iter) untouchable.
// d_ws: f32 w[8192] (32KB); int cnt[64]; int list[64*1024] (256KB);
//       Sb f32[4][4096][64] @ +1MB (4MB); P f32[8192][8][64] @ +8MB (16MB).

typedef unsigned short u16;
typedef unsigned int u32;
typedef __attribute__((ext_vector_type(8))) short short8;
typedef __attribute__((ext_vector_type(4))) float f32x4;

__device__ __forceinline__ float bf2f(u16 u) {
    u32 v = ((u32)u) << 16; float f; __builtin_memcpy(&f, &v, 4); return f;
}
__device__ __forceinline__ u16 f2bf(float f) {  // RNE
    u32 u; __builtin_memcpy(&u, &f, 4);
    u32 r = u + 0x7fff + ((u >> 16) & 1);
    return (u16)(r >> 16);
}
__device__ __forceinline__ u32 pack2(float a, float b) {
    return ((u32)f2bf(b) << 16) | (u32)f2bf(a);
}

#define T_TOKENS 4096
#define DDIM 1024
#define NEXP 64
#define RDIM 64
#define LCAP 1024
#define OUT_IDX_OFF 262144
#define OUT_W_OFF 270336

struct LdBF {
    const u16* p;
    __device__ __forceinline__ float4 ld4(size_t i) const {
        ushort4 v = *(const ushort4*)(p + i);
        return make_float4(bf2f(v.x), bf2f(v.y), bf2f(v.z), bf2f(v.w));
    }
    __device__ __forceinline__ float ld1(size_t i) const { return bf2f(p[i]); }
};
struct LdF32 {
    const float* p;
    __device__ __forceinline__ float4 ld4(size_t i) const { return *(const float4*)(p + i); }
    __device__ __forceinline__ float ld1(size_t i) const { return p[i]; }
};

// in-block dtype probe: 1 if f32, 0 if bf16 (all blocks same verdict).
__device__ __forceinline__ int detect_f32(const u16* x, int* lds_cnt) {
    if (threadIdx.x == 0) *lds_cnt = 0;
    __syncthreads();
    if (threadIdx.x < 256) {
        unsigned e = (x[threadIdx.x] >> 7) & 0xFF;
        if (e >= 0x68 && e <= 0x88) atomicAdd(lds_cnt, 1);
    }
    __syncthreads();
    int f = (*lds_cnt < 200) ? 1 : 0;
    __syncthreads();
    return f;
}

// ---------------- Kernel A: score partials, persistent-rw K-quarter -------
// 256 blocks x 256 thr: q = bid&3 (k in [256q,256q+256)), p = bid>>2
// (tokens [64p, 64p+64), 8 groups of 8). wt4[4][64][68] staged ONCE
// (2-set pipelined issue); per group: stage xs4[4][8][68] from prefetched
// regs, 4 chunks x M4xE8 FMA (dd=4*kql+16*wv -- proven mapping), kql
// shfl-reduce, per-wave partials to scW[wv], 4-way fixed-order sum -> Sb.
// 3 barriers/group. LDS ~85KB, 1 block/CU.
template <class LD>
__device__ __forceinline__ void score_body(LD xld, LD rwld,
                                           float* wt4 /*4*64*68*/, float* xs4 /*4*8*68*/,
                                           float* scW /*4*8*65*/, float* Sb) {
    const int tid = threadIdx.x;
    const int q = blockIdx.x & 3;
    const int p = blockIdx.x >> 2;
    const size_t tp0 = (size_t)p * 64;
    const int kq0 = q * 256;
    const int wv = tid >> 6;
    const int lane = tid & 63;
    const int tg = lane & 1;
    const int eg = (lane >> 1) & 7;
    const int kql = (lane >> 4) & 3;
    const int dd = 4 * kql + 16 * wv;

    // ---- stage rw quarter once: 4 chunk-slabs of [64 e][68] (64 k each).
    // per chunk per thread: 4 f4 loads (i4 = tid + 256h: row=i4>>4, kp=i4&15).
    {
        float4 pA[4], pB[4];
#define RW_LOAD(c, P4)                                                            \
        _Pragma("unroll")                                                         \
        for (int h = 0; h < 4; ++h) {                                             \
            int i4 = tid + h * 256;                                               \
            P4[h] = rwld.ld4((size_t)(i4 >> 4) * DDIM + kq0 + (c) * 64 + (i4 & 15) * 4); \
        }
#define RW_WRITE(c, P4)                                                           \
        _Pragma("unroll")                                                         \
        for (int h = 0; h < 4; ++h) {                                             \
            int i4 = tid + h * 256;                                               \
            *(float4*)&wt4[(c) * 4352 + (i4 >> 4) * 68 + (i4 & 15) * 4] = P4[h];  \
        }
        RW_LOAD(0, pA); RW_LOAD(1, pB);
        RW_WRITE(0, pA); RW_LOAD(2, pA);
        RW_WRITE(1, pB); RW_LOAD(3, pB);
        RW_WRITE(2, pA);
        RW_WRITE(3, pB);
#undef RW_LOAD
#undef RW_WRITE
    }

    // x staging tasks: task in {tid, tid+256}: token=task>>6, f4i=task&63.
    const int tk0 = tid >> 6, f40 = tid & 63;          // task tid
    // task tid+256: token = tk0+4, f4i = f40.
    float4 px0, px1;
    px0 = xld.ld4((tp0 + tk0) * DDIM + kq0 + f40 * 4);
    px1 = xld.ld4((tp0 + tk0 + 4) * DDIM + kq0 + f40 * 4);

    for (int it = 0; it < 8; ++it) {
        // stage x group: xs4[chunk][token][pos]
        {
            int c0 = f40 >> 4, pos = (f40 & 15) * 4;
            *(float4*)&xs4[c0 * 544 + tk0 * 68 + pos] = px0;
            *(float4*)&xs4[c0 * 544 + (tk0 + 4) * 68 + pos] = px1;
        }
        __syncthreads();                       // xs (+ wt4 on it==0) visible

        if (it < 7) {                          // prefetch next group's x
            size_t tn = tp0 + (it + 1) * 8;
            px0 = xld.ld4((tn + tk0) * DDIM + kq0 + f40 * 4);
            px1 = xld.ld4((tn + tk0 + 4) * DDIM + kq0 + f40 * 4);
        }

        float acc[4][8];
#pragma unroll
        for (int mi = 0; mi < 4; ++mi)
#pragma unroll
            for (int ei = 0; ei < 8; ++ei) acc[mi][ei] = 0.f;

#pragma unroll
        for (int c = 0; c < 4; ++c) {
            float4 xv[4], wv4[8];
#pragma unroll
            for (int mi = 0; mi < 4; ++mi)
                xv[mi] = *(const float4*)&xs4[c * 544 + (tg + 2 * mi) * 68 + dd];
#pragma unroll
            for (int ei = 0; ei < 8; ++ei)
                wv4[ei] = *(const float4*)&wt4[c * 4352 + (eg + 8 * ei) * 68 + dd];
#pragma unroll
            for (int mi = 0; mi < 4; ++mi)
#pragma unroll
                for (int ei = 0; ei < 8; ++ei)
                    acc[mi][ei] += xv[mi].x * wv4[ei].x + xv[mi].y * wv4[ei].y +
                                   xv[mi].z * wv4[ei].z + xv[mi].w * wv4[ei].w;
        }

        // kql reduce (deterministic xor tree over lane bits 4,5)
#pragma unroll
        for (int mi = 0; mi < 4; ++mi)
#pragma unroll
            for (int ei = 0; ei < 8; ++ei) {
                float v = acc[mi][ei];
                v += __shfl_xor(v, 16, 64);
                v += __shfl_xor(v, 32, 64);
                acc[mi][ei] = v;
            }
        __syncthreads();                       // prev final-sum done w/ scW

        if (kql == 0) {                        // per-wave partials (parallel)
#pragma unroll
            for (int mi = 0; mi < 4; ++mi)
#pragma unroll
                for (int ei = 0; ei < 8; ++ei)
                    scW[wv * 520 + (tg + 2 * mi) * 65 + eg + 8 * ei] = acc[mi][ei];
        }
        __syncthreads();                       // scW visible

        // 4-way fixed-order sum -> Sb (2 cells/thread, coalesced store)
        {
            size_t tg0 = tp0 + it * 8;
#pragma unroll
            for (int hh = 0; hh < 2; ++hh) {
                int cell = tid + hh * 256;
                int t = cell >> 6, e = cell & 63;
                float v = scW[0 * 520 + t * 65 + e] + scW[1 * 520 + t * 65 + e] +
                          scW[2 * 520 + t * 65 + e] + scW[3 * 520 + t * 65 + e];
                Sb[((size_t)q * T_TOKENS + tg0 + t) * 64 + e] = v;
            }
        }
        // no barrier: next xs-write races only with final-sum (disjoint);
        // next compute is fenced by the post-xs-write barrier.
    }
}

__global__ __launch_bounds__(256, 1) void score_part(const void* x, const void* rw,
                                                     float* Sb) {
    __shared__ float wt4[4 * 64 * 68];
    __shared__ float xs4[4 * 8 * 68];
    __shared__ float scW[4 * 8 * 65];
    __shared__ int dc;
    int f = detect_f32((const u16*)x, &dc);
    if (f)
        score_body(LdF32{(const float*)x}, LdF32{(const float*)rw}, wt4, xs4, scW, Sb);
    else
        score_body(LdBF{(const u16*)x}, LdBF{(const u16*)rw}, wt4, xs4, scW, Sb);
}

// ---------------- Kernel A2: top-2 + softmax + outputs + expert lists -----
// 64 blocks x 64 thr; 1 token/thread. score[t][e] = sum of 4 quarter
// partials in fixed order (deterministic). Same scan/tie-break semantics
// as reference (strict >, ascending j).
__global__ __launch_bounds__(64) void topk_softmax(const float* Sb, float* out,
                                                   float* wsW, int* wsCnt,
                                                   int* wsList) {
    int t = blockIdx.x * 64 + threadIdx.x;       // [0, 4096)
    const float* s0 = Sb + (size_t)t * 64;
    const float* s1 = s0 + (size_t)T_TOKENS * 64;
    const float* s2 = s1 + (size_t)T_TOKENS * 64;
    const float* s3 = s2 + (size_t)T_TOKENS * 64;
    float best = -1e30f, secv = -1e30f;
    int bi = 0, si = 0;
    for (int j = 0; j < NEXP; j += 4) {
        float4 a = *(const float4*)(s0 + j);
        float4 b = *(const float4*)(s1 + j);
        float4 c = *(const float4*)(s2 + j);
        float4 d = *(const float4*)(s3 + j);
        float v0 = ((a.x + b.x) + c.x) + d.x;
        float v1 = ((a.y + b.y) + c.y) + d.y;
        float v2 = ((a.z + b.z) + c.z) + d.z;
        float v3 = ((a.w + b.w) + c.w) + d.w;
        if (v0 > best) { secv = best; si = bi; best = v0; bi = j; }
        else if (v0 > secv) { secv = v0; si = j; }
        if (v1 > best) { secv = best; si = bi; best = v1; bi = j + 1; }
        else if (v1 > secv) { secv = v1; si = j + 1; }
        if (v2 > best) { secv = best; si = bi; best = v2; bi = j + 2; }
        else if (v2 > secv) { secv = v2; si = j + 2; }
        if (v3 > best) { secv = best; si = bi; best = v3; bi = j + 3; }
        else if (v3 > secv) { secv = v3; si = j + 3; }
    }
    float w0 = 1.0f / (1.0f + expf(secv - best));
    float w1 = 1.0f - w0;
    out[OUT_IDX_OFF + (size_t)t * 2 + 0] = (float)bi;
    out[OUT_IDX_OFF + (size_t)t * 2 + 1] = (float)si;
    out[OUT_W_OFF + (size_t)t * 2 + 0] = w0;
    out[OUT_W_OFF + (size_t)t * 2 + 1] = w1;
    wsW[t * 2 + 0] = w0;
    wsW[t * 2 + 1] = w1;
    int p0 = atomicAdd(&wsCnt[bi], 1);
    if (p0 < LCAP) wsList[bi * LCAP + p0] = t * 2 + 0;
    int p1 = atomicAdd(&wsCnt[si], 1);
    if (p1 < LCAP) wsList[si * LCAP + p1] = t * 2 + 1;
}

// ---------------- Kernel B: per-expert bf16 MFMA GEMM, K-eighth persist-B --
// 512 blocks: e = bid>>3, oct = bid&7; k window [oct*128, oct*128+128).
// Stage B eighth ONCE; preload expert token list to LDS. Tile loop:
// 2-deep A-prefetch (named reg sets + swap), 4 MFMA, plain stores of raw
// partials to P[t2*512 + oct*64 + col]. No atomics.
template <class LD>
__device__ __forceinline__ void egemm_body(LD xld, LD nld,
                                           const int* wsCnt, const int* wsList,
                                           float* P,
                                           u16* Ab /*16*136*/, u16* Bb /*64*136*/,
                                           int* eL /*1024*/) {
    const int tid = threadIdx.x;
    const int e = blockIdx.x >> 3;
    const int oct = blockIdx.x & 7;
    const int cntE = min(wsCnt[e], LCAP);
    if (cntE <= 0) return;                       // uniform exit
    const int wv = tid >> 6;
    const int lane = tid & 63;
    const int l15 = lane & 15, quad = lane >> 4;
    const size_t nbase = (size_t)e * (DDIM * RDIM);
    const int k0 = oct * 128;

    for (int j = tid; j < cntE; j += 256) eL[j] = wsList[e * LCAP + j];

    {
        const int rq = tid & 15;
        const int kpB = tid >> 4;
        u32* bb = (u32*)Bb;
#pragma unroll
        for (int h = 0; h < 4; ++h) {
            int kp = kpB + h * 16;
            float4 g0 = nld.ld4(nbase + (size_t)(k0 + 2 * kp) * RDIM + rq * 4);
            float4 g1 = nld.ld4(nbase + (size_t)(k0 + 2 * kp + 1) * RDIM + rq * 4);
            bb[(rq * 4 + 0) * 68 + kp] = pack2(g0.x, g1.x);
            bb[(rq * 4 + 1) * 68 + kp] = pack2(g0.y, g1.y);
            bb[(rq * 4 + 2) * 68 + kp] = pack2(g0.z, g1.z);
            bb[(rq * 4 + 3) * 68 + kp] = pack2(g0.w, g1.w);
        }
    }
    __syncthreads();                              // Bb + eL visible

    const int rowA = tid >> 4;
    const int kqA = tid & 15;
    const int ntiles = (cntE + 15) >> 4;

    float4 c0, c1, n0, n1;
    {
        int t2r = eL[min(rowA, cntE - 1)];
        size_t xrow = (size_t)(t2r >> 1) * DDIM + k0;
        c0 = xld.ld4(xrow + kqA * 8);
        c1 = xld.ld4(xrow + kqA * 8 + 4);
    }
    n0 = c0; n1 = c1;
    if (ntiles > 1) {
        int t2r = eL[min(16 + rowA, cntE - 1)];
        size_t xrow = (size_t)(t2r >> 1) * DDIM + k0;
        n0 = xld.ld4(xrow + kqA * 8);
        n1 = xld.ld4(xrow + kqA * 8 + 4);
    }

    for (int ti = 0; ti < ntiles; ++ti) {
        const int base = ti * 16;
        const int valid = min(16, cntE - base);
        if (ti > 0) __syncthreads();
        {
            uint4 w;
            w.x = pack2(c0.x, c0.y);
            w.y = pack2(c0.z, c0.w);
            w.z = pack2(c1.x, c1.y);
            w.w = pack2(c1.z, c1.w);
            *(uint4*)&((u32*)Ab)[rowA * 68 + kqA * 4] = w;
        }
        __syncthreads();
        if (ti + 2 < ntiles) {
            int t2r = eL[min(base + 32 + rowA, cntE - 1)];
            size_t xrow = (size_t)(t2r >> 1) * DDIM + k0;
            c0 = xld.ld4(xrow + kqA * 8);
            c1 = xld.ld4(xrow + kqA * 8 + 4);
        }

        f32x4 acc = {0.f, 0.f, 0.f, 0.f};
#pragma unroll
        for (int ko = 0; ko < 4; ++ko) {
            int kofs = ko * 32 + quad * 8;
            short8 bfr = *(const short8*)&Bb[(16 * wv + l15) * 136 + kofs];
            short8 af = *(const short8*)&Ab[l15 * 136 + kofs];
            acc = __builtin_amdgcn_mfma_f32_16x16x32_bf16(af, bfr, acc, 0, 0, 0);
        }

#pragma unroll
        for (int reg = 0; reg < 4; ++reg) {
            int m = quad * 4 + reg;
            if (m < valid) {
                int t2 = eL[base + m];
                P[(size_t)t2 * 512 + oct * 64 + 16 * wv + l15] = acc[reg];
            }
        }

        float4 s0 = c0, s1 = c1;
        c0 = n0; c1 = n1;
        n0 = s0; n1 = s1;
    }
}

__global__ __launch_bounds__(256, 2) void expert_gemm(const void* x, const void* neurons,
                                                      const int* wsCnt, const int* wsList,
                                                      float* P) {
    __shared__ u16 Ab[16 * 136];
    __shared__ u16 Bb[64 * 136];
    __shared__ int eL[LCAP];
    __shared__ int dc;
    int f = detect_f32((const u16*)x, &dc);
    if (f)
        egemm_body(LdF32{(const float*)x}, LdF32{(const float*)neurons}, wsCnt, wsList, P, Ab, Bb, eL);
    else
        egemm_body(LdBF{(const u16*)x}, LdBF{(const u16*)neurons}, wsCnt, wsList, P, Ab, Bb, eL);
}

// ---------------- Kernel C: combine partials -------------------------------
// out[t][r] = sum_s wsW[2t+s] * sum_oct P[(2t+s)*512 + oct*64 + r].
// 1024 blocks x 256 thr; 1 element/thread; fully coalesced 256B segments.
__global__ __launch_bounds__(256) void combine(const float* P, const float* wsW,
                                               float* out) {
    int i = blockIdx.x * 256 + threadIdx.x;      // [0, 262144)
    int t = i >> 6, r = i & 63;
    const float* p0 = P + (size_t)(2 * t) * 512 + r;
    const float* p1 = P + (size_t)(2 * t + 1) * 512 + r;
    float s0 = 0.f, s1 = 0.f;
#pragma unroll
    for (int o = 0; o < 8; ++o) {
        s0 += p0[o * 64];
        s1 += p1[o * 64];
    }
    out[i] = wsW[2 * t] * s0 + wsW[2 * t + 1] * s1;
}

extern "C" void kernel_launch(void* const* d_in, const int* in_sizes, int n_in,
                              void* d_out, int out_size, void* d_ws, size_t ws_size,
                              hipStream_t stream) {
    const void* x = d_in[0];
    const void* rw = d_in[1];
    const void* neurons = d_in[2];
    float* out = (float*)d_out;

    char* wsc = (char*)d_ws;
    float* wsW = (float*)wsc;                                  // 32 KB
    int* wsCnt = (int*)(wsc + 32 * 1024);                      // 256 B
    int* wsList = (int*)(wsc + 32 * 1024 + 256);               // 256 KB
    float* Sb = (float*)(wsc + (1 << 20));                     // 4 MB @ +1MB
    float* P = (float*)(wsc + (8 << 20));                      // 16 MB @ +8MB

    hipMemsetAsync(wsCnt, 0, 256, stream);
    score_part<<<256, 256, 0, stream>>>(x, rw, Sb);
    topk_softmax<<<64, 64, 0, stream>>>(Sb, out, wsW, wsCnt, wsList);
    expert_gemm<<<512, 256, 0, stream>>>(x, neurons, wsCnt, wsList, P);
    combine<<<1024, 256, 0, stream>>>(P, wsW, out);
}